// Round 5
// baseline (1344.246 us; speedup 1.0000x reference)
//
#include <hip/hip_runtime.h>
#include <stdint.h>

// GraphSAGE fused layer, MI355X (gfx950). All tensors fp32.
// N=16384, D=64. adj = binary fp32 mask (1.074 GB) -> stream once.
//
// R9: adj read is stuck at ~3.4 TB/s across 5 structural variants while pure
// writes do 6.3. Model: per-CU read-concurrency clamp (~40 outstanding 128B
// lines at ~900cy HBM latency -> 5.5 B/cy/CU = 3.4 TB/s chip-wide). Writes
// are posted (no tracking) -> 6.3. Last untested lever: the OTHER read path,
// global_load_lds (direct-to-LDS DMA, no VGPR writeback). If its tracking
// queue is separate/deeper than the vector-return MSHRs, reads can exceed
// 3.4 TB/s; if it shares them, this lands at ~3.4 again and the read roofline
// is established (declare next round).
//
// Structure: one wave per row. Row = 64 KB = 32 chunks x 2 KB. Each chunk =
// 2 global_load_lds_dwordx4 (1 KB/wave each, lane-linear LDS dest). 4 chunks
// in flight (8 calls, 8 KB/wave). Counted s_waitcnt vmcnt(6) per chunk
// (never 0 mid-loop). Extraction: ballot+mbcnt branchless (R8). Tail (X
// gather, GEMV, ReLU, L2-norm) identical to the 1292us baseline.

#define NROWS   16384
#define DDIM    64
#define MAXNNZ  256       // deg ~ Binom(16384, 32/16384): mean 32, sigma 5.7
#define NBLOCKS 4096
#define NCHUNK  32        // 2 KB chunks per 64 KB row

typedef uint32_t u32x4 __attribute__((ext_vector_type(4)));

#define GL2LDS(g, l)                                                        \
    __builtin_amdgcn_global_load_lds(                                       \
        (const __attribute__((address_space(1))) void*)(g),                 \
        (__attribute__((address_space(3))) void*)(l), 16, 0, 0)

#define WAITVM(n) asm volatile("s_waitcnt vmcnt(" #n ")" ::: "memory")

__device__ __forceinline__ int lane_rank(unsigned long long m) {
    return __builtin_amdgcn_mbcnt_hi((uint32_t)(m >> 32),
           __builtin_amdgcn_mbcnt_lo((uint32_t)m, 0));
}

__global__ __launch_bounds__(256, 4) void sage_fused(
    const float* __restrict__ X,     // (N, 64)
    const float* __restrict__ adj,   // (N, N)
    const float* __restrict__ W,     // (128, 64) row-major, L2-hot (32 KB)
    const float* __restrict__ bias,  // (64,)
    float* __restrict__ out)         // (N, 64)
{
    // [wave][slot][2KB chunk as 512 dwords] = 32 KB
    __shared__ uint32_t stage[4][4][512];
    __shared__ int      slist[4][MAXNNZ];   // per-wave nonzero column list
    __shared__ float    scat[4][2 * DDIM];  // per-wave [x_i | h_neigh]

    const int tid  = threadIdx.x;
    const int lane = tid & 63;
    const int w    = tid >> 6;
    const int row  = blockIdx.x * 4 + w;     // one wave per row

    const float* rowp = adj + (size_t)row * NROWS;

    // ---- Prologue: issue chunks 0..3 (8 DMA calls, 8 KB in flight).
#pragma unroll
    for (int c = 0; c < 4; ++c) {
        const float* g = rowp + c * 512 + lane * 4;   // per-lane global src
        uint32_t* lp = &stage[w][c][0];               // wave-uniform LDS dest
        GL2LDS(g,       lp);                          // lane's 16B -> lp+lane*16
        GL2LDS(g + 256, lp + 256);
    }

    int cnt = 0;   // wave-uniform running nonzero count

    // ---- Main: process chunk c (vmcnt(6): 3 younger chunks = 6 calls
    // still in flight -> never drain the DMA queue), then refill slot with
    // chunk c+4. Epilogue drains 6 -> 4 -> 2 -> 0.
#define EXTRACT(C)                                                           \
    {                                                                        \
        __builtin_amdgcn_sched_barrier(0);                                   \
        const u32x4* sp = reinterpret_cast<const u32x4*>(&stage[w][(C) & 3][0]); \
        _Pragma("unroll")                                                    \
        for (int k = 0; k < 2; ++k) {                                        \
            const u32x4 vv = sp[k * 64 + lane];                              \
            const int base = (C) * 512 + k * 256 + lane * 4;                 \
            const uint32_t w4[4] = { vv.x, vv.y, vv.z, vv.w };               \
            _Pragma("unroll")                                                \
            for (int j = 0; j < 4; ++j) {                                    \
                const bool nz = (w4[j] != 0);                                \
                const unsigned long long m = __ballot(nz);                   \
                const int p = cnt + lane_rank(m);                            \
                if (nz && p < MAXNNZ) slist[w][p] = base + j;                \
                cnt += (int)__popcll(m);                                     \
            }                                                                \
        }                                                                    \
    }

    for (int c = 0; c < NCHUNK - 4; ++c) {
        WAITVM(6);
        EXTRACT(c);
        const int cn4 = c + 4;
        const float* g = rowp + cn4 * 512 + lane * 4;
        uint32_t* lp = &stage[w][cn4 & 3][0];
        GL2LDS(g,       lp);
        GL2LDS(g + 256, lp + 256);
    }
    WAITVM(6); EXTRACT(NCHUNK - 4);
    WAITVM(4); EXTRACT(NCHUNK - 3);
    WAITVM(2); EXTRACT(NCHUNK - 2);
    WAITVM(0); EXTRACT(NCHUNK - 1);
#undef EXTRACT

    __builtin_amdgcn_wave_barrier();

    const int nnz = cnt;
    const int cn  = (nnz < MAXNNZ) ? nnz : MAXNNZ;

    // ---- Gather-accumulate neighbor X rows (256 B coalesced reads, cache-hot).
    float acc = 0.0f;
    int k = 0;
    for (; k + 4 <= cn; k += 4) {
        const int j0 = slist[w][k], j1 = slist[w][k + 1];
        const int j2 = slist[w][k + 2], j3 = slist[w][k + 3];
        const float a0 = X[(size_t)j0 * DDIM + lane];
        const float a1 = X[(size_t)j1 * DDIM + lane];
        const float a2 = X[(size_t)j2 * DDIM + lane];
        const float a3 = X[(size_t)j3 * DDIM + lane];
        acc += (a0 + a1) + (a2 + a3);
    }
    for (; k < cn; ++k) acc += X[(size_t)slist[w][k] * DDIM + lane];

    const float xi = X[(size_t)row * DDIM + lane];
    const float h  = (acc + xi) / ((float)nnz + 1.0f);   // deg = rowsum+1 >= 1
    scat[w][lane]        = xi;
    scat[w][DDIM + lane] = h;
    __builtin_amdgcn_wave_barrier();

    // ---- GEMV: z[d] = b[d] + sum_k cat[k] * W[k][d]; W is L1/L2-hot.
    const float bv = bias[lane];
    float z0 = bv, z1 = 0.0f, z2 = 0.0f, z3 = 0.0f;
#pragma unroll 8
    for (int kk = 0; kk < 2 * DDIM; kk += 4) {
        z0 = fmaf(scat[w][kk + 0], W[(kk + 0) * DDIM + lane], z0);
        z1 = fmaf(scat[w][kk + 1], W[(kk + 1) * DDIM + lane], z1);
        z2 = fmaf(scat[w][kk + 2], W[(kk + 2) * DDIM + lane], z2);
        z3 = fmaf(scat[w][kk + 3], W[(kk + 3) * DDIM + lane], z3);
    }
    float z = (z0 + z1) + (z2 + z3);
    z = fmaxf(z, 0.0f);

    // ---- Row L2-norm over the 64 lanes, normalize, store.
    float s2 = z * z;
#pragma unroll
    for (int off = 32; off >= 1; off >>= 1) s2 += __shfl_xor(s2, off);
    const float inv = 1.0f / fmaxf(sqrtf(s2), 1e-12f);
    out[(size_t)row * DDIM + lane] = z * inv;
}

extern "C" void kernel_launch(void* const* d_in, const int* in_sizes, int n_in,
                              void* d_out, int out_size, void* d_ws, size_t ws_size,
                              hipStream_t stream) {
    const float* X   = (const float*)d_in[0];
    const float* adj = (const float*)d_in[1];
    const float* W   = (const float*)d_in[2];
    const float* b   = (const float*)d_in[3];
    float* out = (float*)d_out;
    sage_fused<<<NBLOCKS, 256, 0, stream>>>(X, adj, W, b, out);
}

// Round 6
// 1343.057 us; speedup vs baseline: 1.0009x; 1.0009x over previous
//
#include <hip/hip_runtime.h>
#include <stdint.h>

// GraphSAGE fused layer, MI355X (gfx950). All tensors fp32.
// N=16384, D=64. adj = binary fp32 mask (1.074 GB) -> stream once.
//
// R10: DIAGNOSTIC ROUND. Six adj-read designs (patterns x cache policy x
// occupancy x issue discipline x return path) all sit at ~3.4 TB/s while the
// harness fill writes 6.4. Before declaring the read roofline, close the one
// confound: buffer identity. ws_read_probe streams 1.074 GB from the
// WORKSPACE (known coarse-grained; the 6.4 TB/s fills target it) using R5's
// exact fill-isomorphic pattern. If ws also reads at 3.4 -> chip-global read
// wall, sage is at roofline. If ws reads at 6.3 -> the adj allocation itself
// is the wall (also unfixable kernel-side). sage_fused (R8, best) unchanged.

#define NROWS   16384
#define DDIM    64
#define MAXNNZ  256       // deg ~ Binom(16384, 32/16384): mean 32, sigma 5.7
#define NBLOCKS 4096

#define PROBE_BLOCKS 2048
#define PROBE_TPB    256
#define PROBE_VECS   (16777216)   // 16Mi dwordx4 = 1.0737 GB (same as adj)

typedef uint32_t u32x4 __attribute__((ext_vector_type(4)));

__device__ __forceinline__ int lane_rank(unsigned long long m) {
    return __builtin_amdgcn_mbcnt_hi((uint32_t)(m >> 32),
           __builtin_amdgcn_mbcnt_lo((uint32_t)m, 0));
}

// ---------------------------------------------------------------------------
// Read-rate probe on the workspace buffer (R5's adj_scan address pattern).
// ---------------------------------------------------------------------------
__global__ __launch_bounds__(PROBE_TPB, 4) void ws_read_probe(
    const uint32_t* __restrict__ ws,
    uint32_t* __restrict__ sink)
{
    const u32x4* p = reinterpret_cast<const u32x4*>(ws);
    const int stride = PROBE_BLOCKS * PROBE_TPB;          // 524,288 vecs
    int i = blockIdx.x * PROBE_TPB + threadIdx.x;
    uint32_t acc = 0;
    // PROBE_VECS = 8 iters x 4 x stride. 4 loads in flight per wave.
    for (int it = 0; it < 8; ++it) {
        const u32x4 v0 = __builtin_nontemporal_load(&p[i]);
        const u32x4 v1 = __builtin_nontemporal_load(&p[i + stride]);
        const u32x4 v2 = __builtin_nontemporal_load(&p[i + 2 * stride]);
        const u32x4 v3 = __builtin_nontemporal_load(&p[i + 3 * stride]);
        acc |= (v0.x | v0.y | v0.z | v0.w);
        acc |= (v1.x | v1.y | v1.z | v1.w);
        acc |= (v2.x | v2.y | v2.z | v2.w);
        acc |= (v3.x | v3.y | v3.z | v3.w);
        i += 4 * stride;
    }
    // 2 MB sink write into ws (scratch) -> prevents DCE, negligible traffic.
    sink[blockIdx.x * PROBE_TPB + threadIdx.x] = acc;
}

// ---------------------------------------------------------------------------
// Best-known fused kernel (R8: branchless ballot/mbcnt scan). Unchanged.
// ---------------------------------------------------------------------------
__global__ __launch_bounds__(256, 4) void sage_fused(
    const float* __restrict__ X,     // (N, 64)
    const float* __restrict__ adj,   // (N, N)
    const float* __restrict__ W,     // (128, 64) row-major, L2-hot (32 KB)
    const float* __restrict__ bias,  // (64,)
    float* __restrict__ out)         // (N, 64)
{
    __shared__ int   slist[4][MAXNNZ];   // per-wave nonzero column list
    __shared__ float scat[4][2 * DDIM];  // per-wave [x_i | h_neigh]

    const int tid  = threadIdx.x;
    const int lane = tid & 63;
    const int w    = tid >> 6;
    const int row  = blockIdx.x * 4 + w;     // one wave per row

    const float bv = bias[lane];

    const int start = (row * 7 + (row >> 4)) & 15;
    const u32x4* rowp = reinterpret_cast<const u32x4*>(adj + (size_t)row * NROWS);

    u32x4 buf[2][4];
    {
        const int ss0 = start;
        const int ss1 = (start + 1) & 15;
#pragma unroll
        for (int q = 0; q < 4; ++q)
            buf[0][q] = __builtin_nontemporal_load(&rowp[ss0 * 256 + q * 64 + lane]);
#pragma unroll
        for (int q = 0; q < 4; ++q)
            buf[1][q] = __builtin_nontemporal_load(&rowp[ss1 * 256 + q * 64 + lane]);
    }

    int cnt = 0;   // wave-uniform running nonzero count

#pragma unroll 2
    for (int s = 0; s < 16; ++s) {
        const int cur = s & 1;
        const int ss  = (s + start) & 15;

        u32x4 t[4];
#pragma unroll
        for (int q = 0; q < 4; ++q) t[q] = buf[cur][q];

        if (s < 14) {
            const int ssn = (s + 2 + start) & 15;
#pragma unroll
            for (int q = 0; q < 4; ++q)
                buf[cur][q] = __builtin_nontemporal_load(&rowp[ssn * 256 + q * 64 + lane]);
        }

#pragma unroll
        for (int q = 0; q < 4; ++q) {
            const u32x4 vv = t[q];
            const int base = (ss * 256 + q * 64 + lane) * 4;
            const uint32_t w4[4] = { vv.x, vv.y, vv.z, vv.w };
#pragma unroll
            for (int j = 0; j < 4; ++j) {
                const bool nz = (w4[j] != 0);
                const unsigned long long m = __ballot(nz);
                const int p = cnt + lane_rank(m);
                if (nz && p < MAXNNZ) slist[w][p] = base + j;  // predicated store
                cnt += (int)__popcll(m);                       // uniform update
            }
        }
    }
    __builtin_amdgcn_wave_barrier();

    const int nnz = cnt;
    const int cn  = (nnz < MAXNNZ) ? nnz : MAXNNZ;

    float acc = 0.0f;
    int k = 0;
    for (; k + 4 <= cn; k += 4) {
        const int j0 = slist[w][k], j1 = slist[w][k + 1];
        const int j2 = slist[w][k + 2], j3 = slist[w][k + 3];
        const float a0 = X[(size_t)j0 * DDIM + lane];
        const float a1 = X[(size_t)j1 * DDIM + lane];
        const float a2 = X[(size_t)j2 * DDIM + lane];
        const float a3 = X[(size_t)j3 * DDIM + lane];
        acc += (a0 + a1) + (a2 + a3);
    }
    for (; k < cn; ++k) acc += X[(size_t)slist[w][k] * DDIM + lane];

    const float xi = X[(size_t)row * DDIM + lane];
    const float h  = (acc + xi) / ((float)nnz + 1.0f);   // deg = rowsum+1 >= 1
    scat[w][lane]        = xi;
    scat[w][DDIM + lane] = h;
    __builtin_amdgcn_wave_barrier();

    float z0 = bv, z1 = 0.0f, z2 = 0.0f, z3 = 0.0f;
#pragma unroll 8
    for (int kk = 0; kk < 2 * DDIM; kk += 4) {
        z0 = fmaf(scat[w][kk + 0], W[(kk + 0) * DDIM + lane], z0);
        z1 = fmaf(scat[w][kk + 1], W[(kk + 1) * DDIM + lane], z1);
        z2 = fmaf(scat[w][kk + 2], W[(kk + 2) * DDIM + lane], z2);
        z3 = fmaf(scat[w][kk + 3], W[(kk + 3) * DDIM + lane], z3);
    }
    float z = (z0 + z1) + (z2 + z3);
    z = fmaxf(z, 0.0f);

    float s2 = z * z;
#pragma unroll
    for (int off = 32; off >= 1; off >>= 1) s2 += __shfl_xor(s2, off);
    const float inv = 1.0f / fmaxf(sqrtf(s2), 1e-12f);
    out[(size_t)row * DDIM + lane] = z * inv;
}

extern "C" void kernel_launch(void* const* d_in, const int* in_sizes, int n_in,
                              void* d_out, int out_size, void* d_ws, size_t ws_size,
                              hipStream_t stream) {
    const float* X   = (const float*)d_in[0];
    const float* adj = (const float*)d_in[1];
    const float* W   = (const float*)d_in[2];
    const float* b   = (const float*)d_in[3];
    float* out = (float*)d_out;

    // Diagnostic: read-rate probe on the workspace (needs 1.074 GB + 2 MB).
    const size_t probe_bytes = (size_t)PROBE_VECS * 16;
    const size_t sink_bytes  = (size_t)PROBE_BLOCKS * PROBE_TPB * 4;
    if (d_ws != nullptr && ws_size >= probe_bytes + sink_bytes) {
        const uint32_t* wsr = (const uint32_t*)d_ws;
        uint32_t* sink = (uint32_t*)((char*)d_ws + probe_bytes);
        ws_read_probe<<<PROBE_BLOCKS, PROBE_TPB, 0, stream>>>(wsr, sink);
    }

    sage_fused<<<NBLOCKS, 256, 0, stream>>>(X, adj, W, b, out);
}